// Round 5
// baseline (618.755 us; speedup 1.0000x reference)
//
#include <hip/hip_runtime.h>

#define T_TOK 8192
#define DIM 1024
#define HID 2048
#define NE 8
#define TK 16384   // T_TOK * 2

typedef __bf16 bf16x8 __attribute__((ext_vector_type(8)));
typedef float f32x16 __attribute__((ext_vector_type(16)));

// ---------------- ws layout (bytes) ----------------
#define OFF_XN      0UL            // T*D*2            = 16,777,216
#define OFF_W1B     16777216UL     // E*H*D*2          = 33,554,432  (shuffled; reused as ybuf after gemm1)
#define OFF_W2B     50331648UL     // E*D*H*2          = 33,554,432  (shuffled)
#define OFF_H       83886080UL     // TK*H*2           = 67,108,864
#define OFF_ATOK    150994944UL    // TK*4
#define OFF_INV     151060480UL    // T*8 (int2)
#define OFF_TOPI    151126016UL    // T*4
#define OFF_GATES   151158784UL    // T*8 (float2)
#define OFF_CPART   151224320UL    // 64*8*4
#define OFF_PPART   151226368UL    // 64*8*4
#define OFF_COUNTS  151228416UL    // 8*4
#define OFF_OFFS    151228448UL
#define OFF_CNT2    151228480UL
#define OFF_NT      151228512UL
#define OFF_TMAP    151228544UL    // 136*16

__device__ __forceinline__ unsigned short f2bf(float f) {
    union { float fv; unsigned u; } q; q.fv = f;
    unsigned r = q.u + 0x7fffu + ((q.u >> 16) & 1u);
    return (unsigned short)(r >> 16);
}

__device__ __forceinline__ float bf2f(unsigned short u) {
    union { unsigned u; float f; } q; q.u = ((unsigned)u) << 16;
    return q.f;
}

__device__ __forceinline__ unsigned pack2(float a, float b) {
    return (unsigned)f2bf(a) | ((unsigned)f2bf(b) << 16);
}

// tanh-form GELU on hw exp/rcp.
__device__ __forceinline__ float gelu_fast(float x) {
    float x3 = x * x * x;
    float z2 = 1.5957691216f * (x + 0.044715f * x3);
    float u = __expf(z2);
    float t = 1.0f - 2.0f * __builtin_amdgcn_rcpf(u + 1.0f);
    return 0.5f * x * (1.0f + t);
}

// -------- fp32 -> bf16 shuffle-convert into MFMA fragment order --------
// dst[(((e*NT + nt)*KS + ks)*64 + lane)*8] = src[e][nt*32 + (lane&31)][ks*16 + (lane>>5)*8 + j]
// Both global sides coalesced; transpose via LDS.
__global__ __launch_bounds__(256) void shuffle_kernel(
    const float* __restrict__ src, unsigned short* __restrict__ dst, int N, int K)
{
    __shared__ unsigned short ls[32 * 72];   // row stride 72 shorts (144B, 16B-aligned)
    int NT = N >> 5, KS = K >> 4;
    int bid = blockIdx.x;
    int e = bid / NT, nt = bid % NT;
    int tid = threadIdx.x;
    int row = tid >> 3, kq = tid & 7;        // 32 rows x 8 k-groups (8 floats each)
    int ksl = tid >> 6, ln = tid & 63;       // 4 ks x 64 lanes
    const float* sp = src + ((size_t)(e * N + nt * 32 + row)) * K + kq * 8;
    size_t dbase = (((size_t)e * NT + nt) * KS) * 512 + ln * 8;

    for (int kc = 0; kc < K; kc += 64) {
        float4 f0 = *(const float4*)(sp + kc);
        float4 f1 = *(const float4*)(sp + kc + 4);
        uint4 u;
        u.x = pack2(f0.x, f0.y); u.y = pack2(f0.z, f0.w);
        u.z = pack2(f1.x, f1.y); u.w = pack2(f1.z, f1.w);
        *(uint4*)&ls[row * 72 + kq * 8] = u;
        __syncthreads();
        uint4 o = *(const uint4*)&ls[(ln & 31) * 72 + ksl * 16 + (ln >> 5) * 8];
        *(uint4*)&dst[dbase + (size_t)((kc >> 4) + ksl) * 512] = o;
        __syncthreads();
    }
}

// -------- fused LayerNorm + router --------
__global__ __launch_bounds__(256) void ln_router_kernel(
    const float* __restrict__ x, const float* __restrict__ gw,
    const float* __restrict__ gamma, const float* __restrict__ beta,
    unsigned short* __restrict__ xnb, int* __restrict__ top_idx,
    float2* __restrict__ gates, int* __restrict__ counts_partial,
    float* __restrict__ probs_partial)
{
    __shared__ float sprob[8];
    __shared__ int scnt[8];
    int tid = threadIdx.x;
    if (tid < 8) { sprob[tid] = 0.f; scnt[tid] = 0; }
    __syncthreads();

    int wave = tid >> 6, lane = tid & 63;
    int t = blockIdx.x * 4 + wave;
    const float* xt = x + (size_t)t * DIM;

    float v[16];
    float s = 0.f, sq = 0.f;
#pragma unroll
    for (int j = 0; j < 4; j++) {
        float4 f = *(const float4*)(xt + j * 256 + lane * 4);
        v[4*j+0] = f.x; v[4*j+1] = f.y; v[4*j+2] = f.z; v[4*j+3] = f.w;
        s += f.x + f.y + f.z + f.w;
        sq += f.x*f.x + f.y*f.y + f.z*f.z + f.w*f.w;
    }
#pragma unroll
    for (int o = 32; o > 0; o >>= 1) { s += __shfl_xor(s, o); sq += __shfl_xor(sq, o); }
    float mean = s * (1.0f / DIM);
    float var = sq * (1.0f / DIM) - mean * mean;
    float rstd = rsqrtf(var + 1e-5f);

#pragma unroll
    for (int j = 0; j < 4; j++) {
        float4 gm = *(const float4*)(gamma + j * 256 + lane * 4);
        float4 bt = *(const float4*)(beta + j * 256 + lane * 4);
        float x0 = (v[4*j+0] - mean) * rstd * gm.x + bt.x;
        float x1 = (v[4*j+1] - mean) * rstd * gm.y + bt.y;
        float x2 = (v[4*j+2] - mean) * rstd * gm.z + bt.z;
        float x3 = (v[4*j+3] - mean) * rstd * gm.w + bt.w;
        ushort4 u; u.x = f2bf(x0); u.y = f2bf(x1); u.z = f2bf(x2); u.w = f2bf(x3);
        *(ushort4*)(xnb + (size_t)t * DIM + j * 256 + lane * 4) = u;
        v[4*j+0] = x0; v[4*j+1] = x1; v[4*j+2] = x2; v[4*j+3] = x3;
    }

    // router logits in fp64 (top-k stability vs reference)
    double part[8];
#pragma unroll
    for (int e = 0; e < 8; e++) {
        double p = 0.0;
        const float* ge = gw + (size_t)e * DIM;
#pragma unroll
        for (int j = 0; j < 4; j++) {
            float4 g = *(const float4*)(ge + j * 256 + lane * 4);
            p += (double)v[4*j+0] * (double)g.x;
            p += (double)v[4*j+1] * (double)g.y;
            p += (double)v[4*j+2] * (double)g.z;
            p += (double)v[4*j+3] * (double)g.w;
        }
        part[e] = p;
    }
#pragma unroll
    for (int o = 32; o > 0; o >>= 1)
#pragma unroll
        for (int e = 0; e < 8; e++) part[e] += __shfl_xor(part[e], o);

    if (lane == 0) {
        double l0 = -1e300; int e0 = -1;
#pragma unroll
        for (int e = 0; e < 8; e++) if (part[e] > l0) { l0 = part[e]; e0 = e; }
        double l1 = -1e300; int e1 = -1;
#pragma unroll
        for (int e = 0; e < 8; e++) if (e != e0 && part[e] > l1) { l1 = part[e]; e1 = e; }
        float d = expf((float)(l1 - l0));
        float g0 = 1.0f / (1.0f + d);
        float g1 = d / (1.0f + d);
        top_idx[t] = e0 | (e1 << 8);
        gates[t] = make_float2(g0, g1);
        atomicAdd(&scnt[e0], 1);
        atomicAdd(&scnt[e1], 1);
        float pe[8]; float sum = 0.f;
#pragma unroll
        for (int e = 0; e < 8; e++) { pe[e] = expf((float)(part[e] - l0)); sum += pe[e]; }
        float inv = 1.0f / sum;
#pragma unroll
        for (int e = 0; e < 8; e++) atomicAdd(&sprob[e], pe[e] * inv);
    }
    __syncthreads();
    if (tid < 8) {
        int bin = (blockIdx.x & 63) * 8 + tid;
        atomicAdd(&probs_partial[bin], sprob[tid]);
        atomicAdd(&counts_partial[bin], scnt[tid]);
    }
}

// -------- finalize (64-thread parallel reduce): counts, offsets, tiles, lb --------
__global__ void finalize_kernel(const int* __restrict__ counts_partial,
                                const float* __restrict__ probs_partial,
                                int* __restrict__ counts, int* __restrict__ offsets,
                                int* __restrict__ cnt2, int* __restrict__ ntiles,
                                int4* __restrict__ tile_map, float* __restrict__ lb_out)
{
    int tid = threadIdx.x;
    int c[8]; float p[8];
#pragma unroll
    for (int e = 0; e < 8; e++) { c[e] = counts_partial[tid*8+e]; p[e] = probs_partial[tid*8+e]; }
#pragma unroll
    for (int o = 32; o > 0; o >>= 1)
#pragma unroll
        for (int e = 0; e < 8; e++) { c[e] += __shfl_xor(c[e], o); p[e] += __shfl_xor(p[e], o); }

    if (tid == 0) {
        int off = 0, nt = 0;
        for (int e = 0; e < 8; e++) {
            offsets[e] = off; counts[e] = c[e]; cnt2[e] = 0;
            for (int m0 = 0; m0 < c[e]; m0 += 128) tile_map[nt++] = make_int4(e, m0, off, c[e]);
            off += c[e];
        }
        *ntiles = nt;
        float avg[8]; float m = 0.f;
        for (int e = 0; e < 8; e++) { avg[e] = p[e] / (float)T_TOK; m += avg[e]; }
        m *= (1.0f / 8.0f);
        float var = 0.f;
        for (int e = 0; e < 8; e++) { float d = avg[e] - m; var += d * d; }
        var *= (1.0f / 7.0f);
        float mm = m + 1e-6f;
        lb_out[0] = (var / (mm * mm)) * 0.01f;
    }
}

// -------- placement: per-expert token lists + inverse slot map --------
__global__ __launch_bounds__(256) void placement_kernel(
    const int* __restrict__ top_idx,
    const int* __restrict__ offsets, int* __restrict__ cnt2,
    int* __restrict__ atok, int2* __restrict__ inv)
{
    __shared__ int lcnt[8];
    __shared__ int lbase[8];
    __shared__ int ltok[4096];
    int tid = threadIdx.x;
    if (tid < 8) lcnt[tid] = 0;
    __syncthreads();
    int t = blockIdx.x * 256 + tid;
    int pk = top_idx[t];
    int e0 = pk & 255, e1 = (pk >> 8) & 255;
    int p0 = atomicAdd(&lcnt[e0], 1); ltok[e0*512+p0] = t;
    int p1 = atomicAdd(&lcnt[e1], 1); ltok[e1*512+p1] = t;
    __syncthreads();
    if (tid < 8) lbase[tid] = offsets[tid] + atomicAdd(&cnt2[tid], lcnt[tid]);
    __syncthreads();
    for (int e = 0; e < 8; e++) {
        int c = lcnt[e], b = lbase[e];
        for (int i = tid; i < c; i += 256) atok[b+i] = ltok[e*512+i];
    }
    inv[t] = make_int2(lbase[e0] + p0, lbase[e1] + p1);
}

// ======== flatmm grouped GEMM: no LDS, no barriers ========
// wave tile 64x64 (2x2 of 32x32x16), BK=64, ping-pong register prefetch.
// A-frag: lane holds row (wm+mi*32+(lane&31)), k = (lane>>5)*8 + step*16.
// B-frag: from pre-shuffled weights, contiguous 1KB per (n32,ks): base + lane*16B.

#define G_LOAD(buf, k0)                                                              \
    do {                                                                             \
        _Pragma("unroll")                                                            \
        for (int st = 0; st < 4; st++) {                                             \
            Af[buf][0][st] = *(const bf16x8*)(a0 + (k0) + st * 16);                  \
            Af[buf][1][st] = *(const bf16x8*)(a1 + (k0) + st * 16);                  \
            Bf[buf][0][st] = *(const bf16x8*)(b0 + (size_t)(((k0) >> 4) + st) * 512);\
            Bf[buf][1][st] = *(const bf16x8*)(b1 + (size_t)(((k0) >> 4) + st) * 512);\
        }                                                                            \
    } while (0)

#define G_MFMA(buf)                                                                  \
    do {                                                                             \
        _Pragma("unroll")                                                            \
        for (int st = 0; st < 4; st++) {                                             \
            acc[0][0] = __builtin_amdgcn_mfma_f32_32x32x16_bf16(Af[buf][0][st], Bf[buf][0][st], acc[0][0], 0, 0, 0); \
            acc[0][1] = __builtin_amdgcn_mfma_f32_32x32x16_bf16(Af[buf][0][st], Bf[buf][1][st], acc[0][1], 0, 0, 0); \
            acc[1][0] = __builtin_amdgcn_mfma_f32_32x32x16_bf16(Af[buf][1][st], Bf[buf][0][st], acc[1][0], 0, 0, 0); \
            acc[1][1] = __builtin_amdgcn_mfma_f32_32x32x16_bf16(Af[buf][1][st], Bf[buf][1][st], acc[1][1], 0, 0, 0); \
        }                                                                            \
    } while (0)

// GEMM1: h[slot] = gelu(xn[atok[slot]] @ w1[e]^T)
__global__ __launch_bounds__(256) void gemm1_kernel(
    const unsigned short* __restrict__ xnb, const unsigned short* __restrict__ w1s,
    unsigned short* __restrict__ hbuf, const int* __restrict__ atok,
    const int4* __restrict__ tile_map, const int* __restrict__ ntiles)
{
    if ((int)blockIdx.y >= *ntiles) return;
    int4 tm = tile_map[blockIdx.y];
    int e = tm.x, m0 = tm.y, base = tm.z, cnt = tm.w;
    int n0 = blockIdx.x * 128;

    int tid = threadIdx.x, lane = tid & 63, wave = tid >> 6;
    int wm = (wave >> 1) * 64, wn = (wave & 1) * 64;
    int r32 = lane & 31, hl = lane >> 5;

    int ra = m0 + wm + r32;      if (ra >= cnt) ra = 0;
    int rb = m0 + wm + 32 + r32; if (rb >= cnt) rb = 0;
    int t0 = atok[base + ra], t1 = atok[base + rb];
    const unsigned short* a0 = xnb + (size_t)t0 * DIM + hl * 8;
    const unsigned short* a1 = xnb + (size_t)t1 * DIM + hl * 8;
    int n32 = (n0 + wn) >> 5;    // first of this wave's two n-tiles
    const unsigned short* b0 = w1s + (((size_t)e * (HID/32) + n32 + 0) * (DIM/16)) * 512 + lane * 8;
    const unsigned short* b1 = w1s + (((size_t)e * (HID/32) + n32 + 1) * (DIM/16)) * 512 + lane * 8;

    bf16x8 Af[2][2][4], Bf[2][2][4];
    f32x16 acc[2][2] = {};

    G_LOAD(0, 0);
    for (int k0 = 0; k0 < DIM; k0 += 128) {
        G_LOAD(1, k0 + 64);
        G_MFMA(0);
        if (k0 + 128 < DIM) G_LOAD(0, k0 + 128);
        G_MFMA(1);
    }

#pragma unroll
    for (int mi = 0; mi < 2; mi++)
#pragma unroll
        for (int ri = 0; ri < 16; ri++) {
            int rowl = (ri & 3) + 8 * (ri >> 2) + 4 * hl;
            int m = wm + mi * 32 + rowl;
            if (m0 + m < cnt) {
                size_t hrow = (size_t)(base + m0 + m) * HID + n0;
#pragma unroll
                for (int ni = 0; ni < 2; ni++)
                    hbuf[hrow + wn + ni * 32 + r32] = f2bf(gelu_fast(acc[mi][ni][ri]));
            }
        }
}

// GEMM2: ybuf[slot] = h[slot] @ w2[e]^T   (gate applied in combine)
__global__ __launch_bounds__(256) void gemm2_kernel(
    const unsigned short* __restrict__ hbuf, const unsigned short* __restrict__ w2s,
    unsigned short* __restrict__ ybuf,
    const int4* __restrict__ tile_map, const int* __restrict__ ntiles)
{
    if ((int)blockIdx.y >= *ntiles) return;
    int4 tm = tile_map[blockIdx.y];
    int e = tm.x, m0 = tm.y, base = tm.z, cnt = tm.w;
    int n0 = blockIdx.x * 128;

    int tid = threadIdx.x, lane = tid & 63, wave = tid >> 6;
    int wm = (wave >> 1) * 64, wn = (wave & 1) * 64;
    int r32 = lane & 31, hl = lane >> 5;

    int ra = m0 + wm + r32;      if (ra >= cnt) ra = 0;
    int rb = m0 + wm + 32 + r32; if (rb >= cnt) rb = 0;
    const unsigned short* a0 = hbuf + (size_t)(base + ra) * HID + hl * 8;
    const unsigned short* a1 = hbuf + (size_t)(base + rb) * HID + hl * 8;
    int n32 = (n0 + wn) >> 5;
    const unsigned short* b0 = w2s + (((size_t)e * (DIM/32) + n32 + 0) * (HID/16)) * 512 + lane * 8;
    const unsigned short* b1 = w2s + (((size_t)e * (DIM/32) + n32 + 1) * (HID/16)) * 512 + lane * 8;

    bf16x8 Af[2][2][4], Bf[2][2][4];
    f32x16 acc[2][2] = {};

    G_LOAD(0, 0);
    for (int k0 = 0; k0 < HID; k0 += 128) {
        G_LOAD(1, k0 + 64);
        G_MFMA(0);
        if (k0 + 128 < HID) G_LOAD(0, k0 + 128);
        G_MFMA(1);
    }

#pragma unroll
    for (int mi = 0; mi < 2; mi++)
#pragma unroll
        for (int ri = 0; ri < 16; ri++) {
            int rowl = (ri & 3) + 8 * (ri >> 2) + 4 * hl;
            int m = wm + mi * 32 + rowl;
            if (m0 + m < cnt) {
                size_t yrow = (size_t)(base + m0 + m) * DIM + n0;
#pragma unroll
                for (int ni = 0; ni < 2; ni++)
                    ybuf[yrow + wn + ni * 32 + r32] = f2bf(acc[mi][ni][ri]);
            }
        }
}

// -------- combine: out = x + g0*y[slot0] + g1*y[slot1] --------
__global__ __launch_bounds__(256) void combine_kernel(
    const float* __restrict__ x, const unsigned short* __restrict__ ybuf,
    const int2* __restrict__ inv, const float2* __restrict__ gates,
    float* __restrict__ out)
{
    int tid = threadIdx.x;
    int wave = tid >> 6, lane = tid & 63;
    int t = blockIdx.x * 4 + wave;
    int2 sl = inv[t];
    float2 g = gates[t];
    const float* xr = x + (size_t)t * DIM;
    const unsigned short* y0 = ybuf + (size_t)sl.x * DIM;
    const unsigned short* y1 = ybuf + (size_t)sl.y * DIM;
    float* orow = out + (size_t)t * DIM;
#pragma unroll
    for (int j = 0; j < 4; j++) {
        int idx = j * 256 + lane * 4;
        float4 xv = *(const float4*)(xr + idx);
        ushort4 a = *(const ushort4*)(y0 + idx);
        ushort4 b = *(const ushort4*)(y1 + idx);
        float4 o;
        o.x = xv.x + g.x * bf2f(a.x) + g.y * bf2f(b.x);
        o.y = xv.y + g.x * bf2f(a.y) + g.y * bf2f(b.y);
        o.z = xv.z + g.x * bf2f(a.z) + g.y * bf2f(b.z);
        o.w = xv.w + g.x * bf2f(a.w) + g.y * bf2f(b.w);
        *(float4*)(orow + idx) = o;
    }
}

extern "C" void kernel_launch(void* const* d_in, const int* in_sizes, int n_in,
                              void* d_out, int out_size, void* d_ws, size_t ws_size,
                              hipStream_t stream) {
    (void)in_sizes; (void)n_in; (void)out_size; (void)ws_size;
    const float* x     = (const float*)d_in[0];
    const float* gw    = (const float*)d_in[1];
    const float* w1    = (const float*)d_in[2];
    const float* w2    = (const float*)d_in[3];
    const float* gamma = (const float*)d_in[4];
    const float* beta  = (const float*)d_in[5];
    float* out = (float*)d_out;
    char* ws = (char*)d_ws;

    unsigned short* xnb  = (unsigned short*)(ws + OFF_XN);
    unsigned short* w1s  = (unsigned short*)(ws + OFF_W1B);
    unsigned short* w2s  = (unsigned short*)(ws + OFF_W2B);
    unsigned short* hbuf = (unsigned short*)(ws + OFF_H);
    unsigned short* ybuf = (unsigned short*)(ws + OFF_W1B);  // reuse w1s after gemm1
    int*    atok    = (int*)(ws + OFF_ATOK);
    int2*   inv     = (int2*)(ws + OFF_INV);
    int*    topi    = (int*)(ws + OFF_TOPI);
    float2* gates   = (float2*)(ws + OFF_GATES);
    int*    cpart   = (int*)(ws + OFF_CPART);
    float*  ppart   = (float*)(ws + OFF_PPART);
    int*    counts  = (int*)(ws + OFF_COUNTS);
    int*    offsets = (int*)(ws + OFF_OFFS);
    int*    cnt2    = (int*)(ws + OFF_CNT2);
    int*    ntiles  = (int*)(ws + OFF_NT);
    int4*   tmap    = (int4*)(ws + OFF_TMAP);

    hipMemsetAsync(ws + OFF_CPART, 0, 4096, stream);

    // shuffle-convert weights into fragment order
    shuffle_kernel<<<NE * (HID/32), 256, 0, stream>>>(w1, w1s, HID, DIM);
    shuffle_kernel<<<NE * (DIM/32), 256, 0, stream>>>(w2, w2s, DIM, HID);

    ln_router_kernel<<<T_TOK / 4, 256, 0, stream>>>(x, gw, gamma, beta, xnb, topi, gates, cpart, ppart);
    finalize_kernel<<<1, 64, 0, stream>>>(cpart, ppart, counts, offsets, cnt2, ntiles, tmap,
                                          out + (size_t)T_TOK * DIM);
    placement_kernel<<<T_TOK / 256, 256, 0, stream>>>(topi, offsets, cnt2, atok, inv);

    gemm1_kernel<<<dim3(HID / 128, 136), 256, 0, stream>>>(xnb, w1s, hbuf, atok, tmap, ntiles);
    gemm2_kernel<<<dim3(DIM / 128, 136), 256, 0, stream>>>(hbuf, w2s, ybuf, tmap, ntiles);
    combine_kernel<<<T_TOK / 4, 256, 0, stream>>>(x, ybuf, inv, gates, out);
}